// Round 1
// baseline (325.420 us; speedup 1.0000x reference)
//
#include <hip/hip_runtime.h>
#include <math.h>

#define SPATIAL 262144   // 64^3
#define NVOX    1048576  // 4 * 64^3
#define NVOL    12       // 4 batches * 3 foreground classes
#define INFV    1e12f

// accumulator layout in ws (floats)
#define ACC_SUMP  0   // [16] sum of probs per (b,c)
#define ACC_TP    16  // [16] sum of probs where target==c
#define ACC_CNT   32  // [16] count of target==c
#define ACC_FOCAL 48  // [1]
#define ACC_BOUND 49  // [12] sum of sdf*prob per (b, c-1)
#define ACC_N     64

__global__ void zero_acc_kernel(float* acc) {
    if (threadIdx.x < ACC_N) acc[threadIdx.x] = 0.0f;
}

__global__ __launch_bounds__(256) void reduce_kernel(
        const float* __restrict__ preds, const int* __restrict__ targets,
        float* __restrict__ acc) {
    int g = blockIdx.x * 256 + threadIdx.x;
    int b = g >> 18;                 // SPATIAL = 2^18
    int sp = g & (SPATIAL - 1);
    const float* pb = preds + (size_t)b * 4 * SPATIAL + sp;
    float p0 = pb[0 * SPATIAL], p1 = pb[1 * SPATIAL];
    float p2 = pb[2 * SPATIAL], p3 = pb[3 * SPATIAL];
    int t = targets[g];
    float m = fmaxf(fmaxf(p0, p1), fmaxf(p2, p3));
    float e0 = expf(p0 - m), e1 = expf(p1 - m), e2 = expf(p2 - m), e3 = expf(p3 - m);
    float s = e0 + e1 + e2 + e3;
    float inv = 1.0f / s;
    float q0 = e0 * inv, q1 = e1 * inv, q2 = e2 * inv, q3 = e3 * inv;
    float lse = m + logf(s);
    float pt_logit = (t == 0) ? p0 : (t == 1) ? p1 : (t == 2) ? p2 : p3;
    float ce = lse - pt_logit;
    float pt = expf(-ce);
    float om = 1.0f - pt;
    float focal = om * om * ce;

    float vals[13];
    vals[0] = q0; vals[1] = q1; vals[2] = q2; vals[3] = q3;
    vals[4] = (t == 0) ? q0 : 0.f; vals[5] = (t == 1) ? q1 : 0.f;
    vals[6] = (t == 2) ? q2 : 0.f; vals[7] = (t == 3) ? q3 : 0.f;
    vals[8]  = (t == 0) ? 1.f : 0.f; vals[9]  = (t == 1) ? 1.f : 0.f;
    vals[10] = (t == 2) ? 1.f : 0.f; vals[11] = (t == 3) ? 1.f : 0.f;
    vals[12] = focal;

    #pragma unroll
    for (int k = 0; k < 13; ++k) {
        float v = vals[k];
        #pragma unroll
        for (int off = 32; off > 0; off >>= 1)
            v += __shfl_down(v, off, 64);
        vals[k] = v;
    }

    __shared__ float sacc[13];
    if (threadIdx.x < 13) sacc[threadIdx.x] = 0.0f;
    __syncthreads();
    if ((threadIdx.x & 63) == 0) {
        #pragma unroll
        for (int k = 0; k < 13; ++k)
            atomicAdd(&sacc[k], vals[k]);
    }
    __syncthreads();
    int tid = threadIdx.x;
    if (tid < 13) {
        int dst = (tid < 4)  ? (ACC_SUMP + b * 4 + tid)
                : (tid < 8)  ? (ACC_TP   + b * 4 + (tid - 4))
                : (tid < 12) ? (ACC_CNT  + b * 4 + (tid - 8))
                : ACC_FOCAL;
        atomicAdd(&acc[dst], sacc[tid]);
    }
}

// DT along x. One (v,z) slice per block. Seed from targets (fused init).
template<bool INVERT>
__global__ __launch_bounds__(256) void dt_pass_x(
        const int* __restrict__ targets, float* __restrict__ out) {
    __shared__ float lds[4096];
    int blk = blockIdx.x;
    int v = blk >> 6, z = blk & 63;
    int b = v / 3, cls = (v % 3) + 1;
    const int* tp = targets + b * SPATIAL + z * 4096;
    int t = threadIdx.x;
    #pragma unroll
    for (int k = 0; k < 16; ++k) {
        int idx = k * 256 + t;
        bool in = (tp[idx] == cls);
        bool seed = INVERT ? !in : in;
        lds[idx] = seed ? 0.0f : INFV;
    }
    __syncthreads();
    int w = t >> 6, lane = t & 63;
    float fi = (float)lane;
    float* outp = out + (size_t)v * SPATIAL + z * 4096;
    for (int yy = 0; yy < 16; ++yy) {
        int y = w * 16 + yy;
        const float* L = lds + y * 64;
        float a = 3.0e38f;
        #pragma unroll
        for (int j = 0; j < 64; ++j) {
            float d = fi - (float)j;
            a = fminf(a, fmaf(d, d, L[j]));
        }
        outp[y * 64 + lane] = a;
    }
}

// DT along y (AXIS=1, fixed z) or z (AXIS=2, fixed y). Optional sqrt on output.
template<int AXIS, bool SQRT>
__global__ __launch_bounds__(256) void dt_pass_yz(
        const float* __restrict__ in, float* __restrict__ out) {
    __shared__ float lds[4096];
    int blk = blockIdx.x;
    int v = blk >> 6, fixed = blk & 63;
    size_t vol = (size_t)v * SPATIAL;
    int t = threadIdx.x;
    #pragma unroll
    for (int k = 0; k < 16; ++k) {
        int idx = k * 256 + t;
        size_t g;
        if (AXIS == 1) g = vol + (size_t)fixed * 4096 + idx;
        else { int zz = idx >> 6, x = idx & 63; g = vol + (size_t)zz * 4096 + fixed * 64 + x; }
        lds[idx] = in[g];
    }
    __syncthreads();
    int x = t & 63, w = t >> 6;
    float a[16];
    #pragma unroll
    for (int k = 0; k < 16; ++k) a[k] = 3.0e38f;
    for (int j = 0; j < 64; ++j) {
        float val = lds[j * 64 + x];
        float fj = (float)j;
        #pragma unroll
        for (int k = 0; k < 16; ++k) {
            float d = (float)(w * 16 + k) - fj;
            a[k] = fminf(a[k], fmaf(d, d, val));
        }
    }
    #pragma unroll
    for (int k = 0; k < 16; ++k) {
        int i = w * 16 + k;
        size_t g;
        if (AXIS == 1) g = vol + (size_t)fixed * 4096 + (size_t)i * 64 + x;
        else           g = vol + (size_t)i * 4096 + (size_t)fixed * 64 + x;
        out[g] = SQRT ? sqrtf(a[k]) : a[k];
    }
}

// Final z-pass of EDT2: dist_in = sqrt(dt), sdf_val = sdf_out - dist_in,
// recompute softmax prob of class cls, reduce sum(sdf*prob) per volume.
__global__ __launch_bounds__(256) void dt_pass_z_final(
        const float* __restrict__ in, const float* __restrict__ sdf,
        const float* __restrict__ preds, float* __restrict__ acc) {
    __shared__ float lds[4096];
    int blk = blockIdx.x;
    int v = blk >> 6, y = blk & 63;
    int b = v / 3, cls = (v % 3) + 1;
    size_t vol = (size_t)v * SPATIAL;
    int t = threadIdx.x;
    #pragma unroll
    for (int k = 0; k < 16; ++k) {
        int idx = k * 256 + t;
        int zz = idx >> 6, x = idx & 63;
        lds[idx] = in[vol + (size_t)zz * 4096 + y * 64 + x];
    }
    __syncthreads();
    int x = t & 63, w = t >> 6;
    float a[16];
    #pragma unroll
    for (int k = 0; k < 16; ++k) a[k] = 3.0e38f;
    for (int j = 0; j < 64; ++j) {
        float val = lds[j * 64 + x];
        float fj = (float)j;
        #pragma unroll
        for (int k = 0; k < 16; ++k) {
            float d = (float)(w * 16 + k) - fj;
            a[k] = fminf(a[k], fmaf(d, d, val));
        }
    }
    float partial = 0.0f;
    const float* pbase = preds + (size_t)b * 4 * SPATIAL;
    #pragma unroll
    for (int k = 0; k < 16; ++k) {
        int i = w * 16 + k;  // z coordinate
        size_t sp = (size_t)i * 4096 + (size_t)y * 64 + x;
        float din = sqrtf(a[k]);
        float sv = sdf[vol + sp] - din;
        float p0 = pbase[sp], p1 = pbase[SPATIAL + sp];
        float p2 = pbase[2 * SPATIAL + sp], p3 = pbase[3 * SPATIAL + sp];
        float m = fmaxf(fmaxf(p0, p1), fmaxf(p2, p3));
        float e0 = expf(p0 - m), e1 = expf(p1 - m);
        float e2 = expf(p2 - m), e3 = expf(p3 - m);
        float s = e0 + e1 + e2 + e3;
        float ec = (cls == 1) ? e1 : (cls == 2) ? e2 : e3;
        partial += sv * (ec / s);
    }
    #pragma unroll
    for (int off = 32; off > 0; off >>= 1)
        partial += __shfl_down(partial, off, 64);
    __shared__ float ws4[4];
    if ((t & 63) == 0) ws4[w] = partial;
    __syncthreads();
    if (t == 0) {
        float tot = ws4[0] + ws4[1] + ws4[2] + ws4[3];
        atomicAdd(&acc[ACC_BOUND + v], tot);
    }
}

__global__ void finalize_kernel(const float* __restrict__ acc, float* __restrict__ out) {
    if (threadIdx.x != 0 || blockIdx.x != 0) return;
    float tsum = 0.0f;
    for (int i = 0; i < 16; ++i) {
        float TP = acc[ACC_TP + i];
        float S  = acc[ACC_SUMP + i];
        float CN = acc[ACC_CNT + i];
        float FP = S - TP;
        float FN = CN - TP;
        tsum += (TP + 1e-5f) / (TP + 0.3f * FP + 0.7f * FN + 1e-5f);
    }
    float l_dice = 1.0f - tsum / 16.0f;
    float l_main = acc[ACC_FOCAL] / (float)NVOX;
    float bsum = 0.0f;
    for (int v = 0; v < NVOL; ++v) {
        int b = v / 3, c = (v % 3) + 1;
        float CN = acc[ACC_CNT + b * 4 + c];
        float contrib;
        if (CN <= 0.0f) contrib = 0.0f;                                   // empty mask: excluded
        else if (CN >= (float)SPATIAL) contrib = -acc[ACC_SUMP + b * 4 + c] / (float)SPATIAL; // full mask: sdf=-1
        else contrib = acc[ACC_BOUND + v] / (float)SPATIAL;
        bsum += contrib;
    }
    float l_bound = bsum / (12.0f + 1e-8f);
    out[0] = l_dice + l_main + 0.01f * l_bound;
}

extern "C" void kernel_launch(void* const* d_in, const int* in_sizes, int n_in,
                              void* d_out, int out_size, void* d_ws, size_t ws_size,
                              hipStream_t stream) {
    const float* preds = (const float*)d_in[0];
    const int* targets = (const int*)d_in[1];
    float* out = (float*)d_out;
    float* ws = (float*)d_ws;
    float* acc = ws;                                  // 64 floats
    float* sdf = ws + ACC_N;                          // NVOL*SPATIAL
    float* dtA = sdf + (size_t)NVOL * SPATIAL;        // NVOL*SPATIAL
    float* dtB = dtA + (size_t)NVOL * SPATIAL;        // NVOL*SPATIAL

    hipLaunchKernelGGL(zero_acc_kernel, dim3(1), dim3(64), 0, stream, acc);
    hipLaunchKernelGGL(reduce_kernel, dim3(NVOX / 256), dim3(256), 0, stream,
                       preds, targets, acc);
    // EDT1: seed = mask -> dist_out -> sdf
    hipLaunchKernelGGL((dt_pass_x<false>), dim3(NVOL * 64), dim3(256), 0, stream, targets, dtA);
    hipLaunchKernelGGL((dt_pass_yz<1, false>), dim3(NVOL * 64), dim3(256), 0, stream, dtA, dtB);
    hipLaunchKernelGGL((dt_pass_yz<2, true>), dim3(NVOL * 64), dim3(256), 0, stream, dtB, sdf);
    // EDT2: seed = ~mask -> dist_in, fused with sdf combine + prob + reduction
    hipLaunchKernelGGL((dt_pass_x<true>), dim3(NVOL * 64), dim3(256), 0, stream, targets, dtA);
    hipLaunchKernelGGL((dt_pass_yz<1, false>), dim3(NVOL * 64), dim3(256), 0, stream, dtA, dtB);
    hipLaunchKernelGGL(dt_pass_z_final, dim3(NVOL * 64), dim3(256), 0, stream,
                       dtB, sdf, preds, acc);
    hipLaunchKernelGGL(finalize_kernel, dim3(1), dim3(64), 0, stream, acc, out);
}

// Round 2
// 175.866 us; speedup vs baseline: 1.8504x; 1.8504x over previous
//
#include <hip/hip_runtime.h>
#include <math.h>

#define SPATIAL 262144   // 64^3
#define NVOX    1048576  // 4 * 64^3
#define NVOL    12       // 4 batches * 3 foreground classes
#define INFV    1e12f

// accumulator layout in ws (floats)
#define ACC_SUMP  0   // [16] sum of probs per (b,c)
#define ACC_TP    16  // [16] sum of probs where target==c
#define ACC_CNT   32  // [16] count of target==c
#define ACC_FOCAL 48  // [4]  focal sum per batch
#define ACC_BOUND 52  // [12] sum of sdf*prob per (b, c-1)
#define ACC_N     64
#define NPART     13  // per-block partial values in reduce

__global__ void zero_acc_kernel(float* acc) {
    if (threadIdx.x < ACC_N) acc[threadIdx.x] = 0.0f;
}

__device__ __forceinline__ void voxel_accum(float p0, float p1, float p2, float p3,
                                            int t, float* loc) {
    float m = fmaxf(fmaxf(p0, p1), fmaxf(p2, p3));
    float e0 = expf(p0 - m), e1 = expf(p1 - m), e2 = expf(p2 - m), e3 = expf(p3 - m);
    float s = e0 + e1 + e2 + e3;
    float inv = 1.0f / s;
    float q0 = e0 * inv, q1 = e1 * inv, q2 = e2 * inv, q3 = e3 * inv;
    float lse = m + logf(s);
    float pl = (t == 0) ? p0 : (t == 1) ? p1 : (t == 2) ? p2 : p3;
    float ce = lse - pl;
    float pt = expf(-ce);
    float om = 1.0f - pt;
    loc[0] += q0; loc[1] += q1; loc[2] += q2; loc[3] += q3;
    if (t == 0)      { loc[4] += q0; loc[8]  += 1.f; }
    else if (t == 1) { loc[5] += q1; loc[9]  += 1.f; }
    else if (t == 2) { loc[6] += q2; loc[10] += 1.f; }
    else             { loc[7] += q3; loc[11] += 1.f; }
    loc[12] += om * om * ce;
}

// 256 blocks; block bb: batch b = bb>>6, chunk = bb&63 (4096 voxels).
// No global atomics: per-block partials -> ws.
__global__ __launch_bounds__(256) void reduce_kernel(
        const float* __restrict__ preds, const int* __restrict__ targets,
        float* __restrict__ partials) {
    int bb = blockIdx.x;
    int b = bb >> 6, chunk = bb & 63;
    int tid = threadIdx.x;
    const float* pb = preds + (size_t)b * 4 * SPATIAL;
    const int* tb = targets + b * SPATIAL;
    float loc[NPART];
    #pragma unroll
    for (int k = 0; k < NPART; ++k) loc[k] = 0.0f;

    for (int it = 0; it < 4; ++it) {
        int sp = chunk * 4096 + it * 1024 + tid * 4;
        float4 P0 = *(const float4*)(pb + 0 * SPATIAL + sp);
        float4 P1 = *(const float4*)(pb + 1 * SPATIAL + sp);
        float4 P2 = *(const float4*)(pb + 2 * SPATIAL + sp);
        float4 P3 = *(const float4*)(pb + 3 * SPATIAL + sp);
        int4   T  = *(const int4*)(tb + sp);
        voxel_accum(P0.x, P1.x, P2.x, P3.x, T.x, loc);
        voxel_accum(P0.y, P1.y, P2.y, P3.y, T.y, loc);
        voxel_accum(P0.z, P1.z, P2.z, P3.z, T.z, loc);
        voxel_accum(P0.w, P1.w, P2.w, P3.w, T.w, loc);
    }

    int lane = tid & 63, w = tid >> 6;
    #pragma unroll
    for (int k = 0; k < NPART; ++k) {
        float v = loc[k];
        #pragma unroll
        for (int off = 32; off > 0; off >>= 1)
            v += __shfl_down(v, off, 64);
        loc[k] = v;
    }
    __shared__ float sred[NPART][4];
    if (lane == 0) {
        #pragma unroll
        for (int k = 0; k < NPART; ++k) sred[k][w] = loc[k];
    }
    __syncthreads();
    if (tid < NPART) {
        float tot = sred[tid][0] + sred[tid][1] + sred[tid][2] + sred[tid][3];
        partials[(b * NPART + tid) * 64 + chunk] = tot;
    }
}

// 52 blocks x 64 threads: reduce 64 chunk-partials per (b, value).
__global__ void stage2_kernel(const float* __restrict__ partials,
                              float* __restrict__ acc) {
    int r = blockIdx.x;           // 0..51
    int b = r / NPART, k = r % NPART;
    int lane = threadIdx.x;       // 64
    float v = partials[(b * NPART + k) * 64 + lane];
    #pragma unroll
    for (int off = 32; off > 0; off >>= 1)
        v += __shfl_down(v, off, 64);
    if (lane == 0) {
        int dst = (k < 4)  ? (ACC_SUMP + b * 4 + k)
                : (k < 8)  ? (ACC_TP   + b * 4 + (k - 4))
                : (k < 12) ? (ACC_CNT  + b * 4 + (k - 8))
                : (ACC_FOCAL + b);
        acc[dst] = v;
    }
}

// squared distance from lane i to nearest set bit in 64-bit row mask m.
// Bit-identical to brute min-plus: seeds contribute exact (i-j)^2; empty row
// yields exactly 1e12 (since 1e12 + d^2 rounds back to 1e12 in fp32).
__device__ __forceinline__ float row_d2(unsigned long long m, int i) {
    if (m == 0ull) return INFV;
    unsigned long long right = m >> i;
    unsigned long long left  = m << (63 - i);
    int dr = right ? __builtin_ctzll(right) : 1000;
    int dl = left  ? __builtin_clzll(left)  : 1000;
    int d = (dr < dl) ? dr : dl;
    return (float)(d * d);
}

// Fused x-DT (ballot trick, both fields) + y-DT (both fields) for one (v,z) slice.
__global__ __launch_bounds__(256) void dtxy_kernel(
        const int* __restrict__ targets,
        float* __restrict__ dtOut, float* __restrict__ dtIn) {
    __shared__ float lo[4096];
    __shared__ float li[4096];
    int blk = blockIdx.x;
    int v = blk >> 6, z = blk & 63;
    int b = v / 3, cls = (v % 3) + 1;
    const int* tp = targets + b * SPATIAL + z * 4096;
    int t = threadIdx.x;
    int lane = t & 63, w = t >> 6;

    #pragma unroll
    for (int k = 0; k < 16; ++k) {
        int y = w * 16 + k;
        int tv = tp[y * 64 + lane];
        unsigned long long m = __ballot(tv == cls);
        lo[y * 64 + lane] = row_d2(m, lane);
        li[y * 64 + lane] = row_d2(~m, lane);
    }
    __syncthreads();

    float ao[16], ai[16];
    #pragma unroll
    for (int k = 0; k < 16; ++k) { ao[k] = 3.0e38f; ai[k] = 3.0e38f; }
    for (int j = 0; j < 64; ++j) {
        float vo = lo[j * 64 + lane];
        float vi = li[j * 64 + lane];
        float fj = (float)j;
        #pragma unroll
        for (int k = 0; k < 16; ++k) {
            float d = (float)(w * 16 + k) - fj;
            ao[k] = fminf(ao[k], fmaf(d, d, vo));
            ai[k] = fminf(ai[k], fmaf(d, d, vi));
        }
    }
    size_t vol = (size_t)v * SPATIAL;
    #pragma unroll
    for (int k = 0; k < 16; ++k) {
        int i = w * 16 + k;
        size_t g = vol + (size_t)z * 4096 + (size_t)i * 64 + lane;
        dtOut[g] = ao[k];
        dtIn[g]  = ai[k];
    }
}

// z-DT on both fields + sdf + softmax prob of cls + volume reduction.
__global__ __launch_bounds__(256) void dtz_final_kernel(
        const float* __restrict__ dtOut, const float* __restrict__ dtIn,
        const float* __restrict__ preds, float* __restrict__ acc) {
    __shared__ float lo[4096];
    __shared__ float li[4096];
    int blk = blockIdx.x;
    int v = blk >> 6, y = blk & 63;
    int b = v / 3, cls = (v % 3) + 1;
    size_t vol = (size_t)v * SPATIAL;
    int t = threadIdx.x;
    int lane = t & 63, w = t >> 6;

    #pragma unroll
    for (int k = 0; k < 16; ++k) {
        int idx = k * 256 + t;
        int zz = idx >> 6, x = idx & 63;
        size_t g = vol + (size_t)zz * 4096 + (size_t)y * 64 + x;
        lo[idx] = dtOut[g];
        li[idx] = dtIn[g];
    }
    __syncthreads();

    float ao[16], ai[16];
    #pragma unroll
    for (int k = 0; k < 16; ++k) { ao[k] = 3.0e38f; ai[k] = 3.0e38f; }
    for (int j = 0; j < 64; ++j) {
        float vo = lo[j * 64 + lane];
        float vi = li[j * 64 + lane];
        float fj = (float)j;
        #pragma unroll
        for (int k = 0; k < 16; ++k) {
            float d = (float)(w * 16 + k) - fj;
            ao[k] = fminf(ao[k], fmaf(d, d, vo));
            ai[k] = fminf(ai[k], fmaf(d, d, vi));
        }
    }

    float partial = 0.0f;
    const float* pbase = preds + (size_t)b * 4 * SPATIAL;
    #pragma unroll
    for (int k = 0; k < 16; ++k) {
        int i = w * 16 + k;  // z coordinate
        size_t sp = (size_t)i * 4096 + (size_t)y * 64 + lane;
        float sv = sqrtf(ao[k]) - sqrtf(ai[k]);
        float p0 = pbase[sp], p1 = pbase[SPATIAL + sp];
        float p2 = pbase[2 * SPATIAL + sp], p3 = pbase[3 * SPATIAL + sp];
        float m = fmaxf(fmaxf(p0, p1), fmaxf(p2, p3));
        float e0 = expf(p0 - m), e1 = expf(p1 - m);
        float e2 = expf(p2 - m), e3 = expf(p3 - m);
        float s = e0 + e1 + e2 + e3;
        float ec = (cls == 1) ? e1 : (cls == 2) ? e2 : e3;
        partial += sv * (ec / s);
    }
    #pragma unroll
    for (int off = 32; off > 0; off >>= 1)
        partial += __shfl_down(partial, off, 64);
    __shared__ float ws4[4];
    if (lane == 0) ws4[w] = partial;
    __syncthreads();
    if (t == 0) {
        float tot = ws4[0] + ws4[1] + ws4[2] + ws4[3];
        atomicAdd(&acc[ACC_BOUND + v], tot);
    }
}

__global__ void finalize_kernel(const float* __restrict__ acc, float* __restrict__ out) {
    if (threadIdx.x != 0 || blockIdx.x != 0) return;
    float tsum = 0.0f;
    for (int i = 0; i < 16; ++i) {
        float TP = acc[ACC_TP + i];
        float S  = acc[ACC_SUMP + i];
        float CN = acc[ACC_CNT + i];
        float FP = S - TP;
        float FN = CN - TP;
        tsum += (TP + 1e-5f) / (TP + 0.3f * FP + 0.7f * FN + 1e-5f);
    }
    float l_dice = 1.0f - tsum / 16.0f;
    float l_main = (acc[ACC_FOCAL] + acc[ACC_FOCAL + 1] +
                    acc[ACC_FOCAL + 2] + acc[ACC_FOCAL + 3]) / (float)NVOX;
    float bsum = 0.0f;
    for (int v = 0; v < NVOL; ++v) {
        int b = v / 3, c = (v % 3) + 1;
        float CN = acc[ACC_CNT + b * 4 + c];
        float contrib;
        if (CN <= 0.0f) contrib = 0.0f;
        else if (CN >= (float)SPATIAL) contrib = -acc[ACC_SUMP + b * 4 + c] / (float)SPATIAL;
        else contrib = acc[ACC_BOUND + v] / (float)SPATIAL;
        bsum += contrib;
    }
    float l_bound = bsum / (12.0f + 1e-8f);
    out[0] = l_dice + l_main + 0.01f * l_bound;
}

extern "C" void kernel_launch(void* const* d_in, const int* in_sizes, int n_in,
                              void* d_out, int out_size, void* d_ws, size_t ws_size,
                              hipStream_t stream) {
    const float* preds = (const float*)d_in[0];
    const int* targets = (const int*)d_in[1];
    float* out = (float*)d_out;
    float* ws = (float*)d_ws;
    float* acc = ws;                                   // 64 floats
    float* partials = ws + ACC_N;                      // 4*13*64 = 3328 floats
    float* dtOut = partials + 4 * NPART * 64;          // NVOL*SPATIAL
    float* dtIn = dtOut + (size_t)NVOL * SPATIAL;      // NVOL*SPATIAL

    hipLaunchKernelGGL(zero_acc_kernel, dim3(1), dim3(64), 0, stream, acc);
    hipLaunchKernelGGL(reduce_kernel, dim3(256), dim3(256), 0, stream,
                       preds, targets, partials);
    hipLaunchKernelGGL(stage2_kernel, dim3(52), dim3(64), 0, stream, partials, acc);
    hipLaunchKernelGGL(dtxy_kernel, dim3(NVOL * 64), dim3(256), 0, stream,
                       targets, dtOut, dtIn);
    hipLaunchKernelGGL(dtz_final_kernel, dim3(NVOL * 64), dim3(256), 0, stream,
                       dtOut, dtIn, preds, acc);
    hipLaunchKernelGGL(finalize_kernel, dim3(1), dim3(64), 0, stream, acc, out);
}

// Round 3
// 111.346 us; speedup vs baseline: 2.9226x; 1.5795x over previous
//
#include <hip/hip_runtime.h>
#include <math.h>

#define SPATIAL 262144   // 64^3
#define NVOX    1048576  // 4 * 64^3
#define NVOL    12       // 4 batches * 3 foreground classes
#define INFV    1e12f

// accumulator layout in ws (floats)
#define ACC_SUMP  0   // [16] sum of probs per (b,c)
#define ACC_TP    16  // [16] sum of probs where target==c
#define ACC_CNT   32  // [16] count of target==c
#define ACC_FOCAL 48  // [4]  focal sum per batch
#define ACC_BOUND 52  // [12] sum of sdf*prob per (b, c-1)
#define ACC_N     64
#define NPART     13  // per-block partial values in reduce
#define RCHUNK    256 // reduce chunks per batch

__global__ void zero_acc_kernel(float* acc) {
    if (threadIdx.x < ACC_N) acc[threadIdx.x] = 0.0f;
}

__device__ __forceinline__ void voxel_accum(float p0, float p1, float p2, float p3,
                                            int t, float* loc) {
    float m = fmaxf(fmaxf(p0, p1), fmaxf(p2, p3));
    float e0 = __expf(p0 - m), e1 = __expf(p1 - m);
    float e2 = __expf(p2 - m), e3 = __expf(p3 - m);
    float s = e0 + e1 + e2 + e3;
    float inv = __builtin_amdgcn_rcpf(s);
    float q0 = e0 * inv, q1 = e1 * inv, q2 = e2 * inv, q3 = e3 * inv;
    float pl = (t == 0) ? p0 : (t == 1) ? p1 : (t == 2) ? p2 : p3;
    float ce = __logf(s) + (m - pl);           // lse - pl
    float qt = (t == 0) ? q0 : (t == 1) ? q1 : (t == 2) ? q2 : q3;  // = exp(-ce)
    float om = 1.0f - qt;
    loc[0] += q0; loc[1] += q1; loc[2] += q2; loc[3] += q3;
    if (t == 0)      { loc[4] += q0; loc[8]  += 1.f; }
    else if (t == 1) { loc[5] += q1; loc[9]  += 1.f; }
    else if (t == 2) { loc[6] += q2; loc[10] += 1.f; }
    else             { loc[7] += q3; loc[11] += 1.f; }
    loc[12] += om * om * ce;
}

// 1024 blocks (4/CU); block bb: batch b = bb>>8, chunk = bb&255 (1024 voxels).
__global__ __launch_bounds__(256) void reduce_kernel(
        const float* __restrict__ preds, const int* __restrict__ targets,
        float* __restrict__ partials) {
    int bb = blockIdx.x;
    int b = bb >> 8, chunk = bb & 255;
    int tid = threadIdx.x;
    const float* pb = preds + (size_t)b * 4 * SPATIAL;
    const int* tb = targets + b * SPATIAL;
    float loc[NPART];
    #pragma unroll
    for (int k = 0; k < NPART; ++k) loc[k] = 0.0f;

    int sp = chunk * 1024 + tid * 4;
    float4 P0 = *(const float4*)(pb + 0 * SPATIAL + sp);
    float4 P1 = *(const float4*)(pb + 1 * SPATIAL + sp);
    float4 P2 = *(const float4*)(pb + 2 * SPATIAL + sp);
    float4 P3 = *(const float4*)(pb + 3 * SPATIAL + sp);
    int4   T  = *(const int4*)(tb + sp);
    voxel_accum(P0.x, P1.x, P2.x, P3.x, T.x, loc);
    voxel_accum(P0.y, P1.y, P2.y, P3.y, T.y, loc);
    voxel_accum(P0.z, P1.z, P2.z, P3.z, T.z, loc);
    voxel_accum(P0.w, P1.w, P2.w, P3.w, T.w, loc);

    int lane = tid & 63, w = tid >> 6;
    #pragma unroll
    for (int k = 0; k < NPART; ++k) {
        float v = loc[k];
        #pragma unroll
        for (int off = 32; off > 0; off >>= 1)
            v += __shfl_down(v, off, 64);
        loc[k] = v;
    }
    __shared__ float sred[NPART][4];
    if (lane == 0) {
        #pragma unroll
        for (int k = 0; k < NPART; ++k) sred[k][w] = loc[k];
    }
    __syncthreads();
    if (tid < NPART) {
        float tot = sred[tid][0] + sred[tid][1] + sred[tid][2] + sred[tid][3];
        partials[(b * NPART + tid) * RCHUNK + chunk] = tot;
    }
}

// 52 blocks x 256 threads: reduce 256 chunk-partials per (b, value).
__global__ __launch_bounds__(256) void stage2_kernel(
        const float* __restrict__ partials, float* __restrict__ acc) {
    int r = blockIdx.x;           // 0..51
    int b = r / NPART, k = r % NPART;
    int tid = threadIdx.x;
    int lane = tid & 63, w = tid >> 6;
    float v = partials[(b * NPART + k) * RCHUNK + tid];
    #pragma unroll
    for (int off = 32; off > 0; off >>= 1)
        v += __shfl_down(v, off, 64);
    __shared__ float sred[4];
    if (lane == 0) sred[w] = v;
    __syncthreads();
    if (tid == 0) {
        float tot = sred[0] + sred[1] + sred[2] + sred[3];
        int dst = (k < 4)  ? (ACC_SUMP + b * 4 + k)
                : (k < 8)  ? (ACC_TP   + b * 4 + (k - 4))
                : (k < 12) ? (ACC_CNT  + b * 4 + (k - 8))
                : (ACC_FOCAL + b);
        acc[dst] = tot;
    }
}

// squared distance from lane i to nearest set bit in 64-bit row mask m.
__device__ __forceinline__ float row_d2(unsigned long long m, int i) {
    if (m == 0ull) return INFV;
    unsigned long long right = m >> i;
    unsigned long long left  = m << (63 - i);
    int dr = right ? __builtin_ctzll(right) : 1000;
    int dl = left  ? __builtin_clzll(left)  : 1000;
    int d = (dr < dl) ? dr : dl;
    return (float)(d * d);
}

// Windowed exact min-plus over both fields. 8 accumulators per thread,
// wave w owns i in [8w, 8w+8). Bit-exact: skipped j satisfy d^2 >= a[k].
#define MINPLUS_BODY(LO, LI, AO, AI, LANE, W)                                   \
    {                                                                           \
        int base = (W) * 8;                                                     \
        _Pragma("unroll")                                                       \
        for (int jj = 0; jj < 8; ++jj) {                                        \
            float vo = LO[(base + jj) * 64 + (LANE)];                           \
            float vi = LI[(base + jj) * 64 + (LANE)];                           \
            _Pragma("unroll")                                                   \
            for (int k = 0; k < 8; ++k) {                                       \
                float d = (float)(k - jj);                                      \
                AO[k] = fminf(AO[k], fmaf(d, d, vo));                           \
                AI[k] = fminf(AI[k], fmaf(d, d, vi));                           \
            }                                                                   \
        }                                                                       \
        int el_max = base;                                                      \
        int er_max = 56 - base;                                                 \
        int t = 1;                                                              \
        while (true) {                                                          \
            float am = 0.0f;                                                    \
            _Pragma("unroll")                                                   \
            for (int k = 0; k < 8; ++k) am = fmaxf(am, fmaxf(AO[k], AI[k]));    \
            _Pragma("unroll")                                                   \
            for (int off = 32; off > 0; off >>= 1)                              \
                am = fmaxf(am, __shfl_xor(am, off, 64));                        \
            int dmax = (int)sqrtf(fmaxf(am - 1.0f, 0.0f));                      \
            int Tl = (dmax < el_max) ? dmax : el_max;                           \
            int Tr = (dmax < er_max) ? dmax : er_max;                           \
            int T = (Tl > Tr) ? Tl : Tr;                                        \
            if (t > T) break;                                                   \
            int tend = (T < t + 3) ? T : (t + 3);                               \
            for (; t <= tend; ++t) {                                            \
                float ft = (float)t;                                            \
                if (t <= Tl) {                                                  \
                    int j = base - t;                                           \
                    float vo = LO[j * 64 + (LANE)];                             \
                    float vi = LI[j * 64 + (LANE)];                             \
                    _Pragma("unroll")                                           \
                    for (int k = 0; k < 8; ++k) {                               \
                        float d = ft + (float)k;                                \
                        AO[k] = fminf(AO[k], fmaf(d, d, vo));                   \
                        AI[k] = fminf(AI[k], fmaf(d, d, vi));                   \
                    }                                                           \
                }                                                               \
                if (t <= Tr) {                                                  \
                    int j = base + 7 + t;                                       \
                    float vo = LO[j * 64 + (LANE)];                             \
                    float vi = LI[j * 64 + (LANE)];                             \
                    float fr = ft + 7.0f;                                       \
                    _Pragma("unroll")                                           \
                    for (int k = 0; k < 8; ++k) {                               \
                        float d = fr - (float)k;                                \
                        AO[k] = fminf(AO[k], fmaf(d, d, vo));                   \
                        AI[k] = fminf(AI[k], fmaf(d, d, vi));                   \
                    }                                                           \
                }                                                               \
            }                                                                   \
        }                                                                       \
    }

// Fused x-DT (ballot, both fields) + windowed y-DT for one (v,z) slice.
__global__ __launch_bounds__(512) void dtxy_kernel(
        const int* __restrict__ targets,
        float* __restrict__ dtOut, float* __restrict__ dtIn) {
    __shared__ float lo[4096];
    __shared__ float li[4096];
    int blk = blockIdx.x;
    int v = blk >> 6, z = blk & 63;
    int b = v / 3, cls = (v % 3) + 1;
    const int* tp = targets + b * SPATIAL + z * 4096;
    int t = threadIdx.x;
    int lane = t & 63, w = t >> 6;   // w in [0,8)

    #pragma unroll
    for (int k = 0; k < 8; ++k) {
        int y = w * 8 + k;
        int tv = tp[y * 64 + lane];
        unsigned long long m = __ballot(tv == cls);
        lo[y * 64 + lane] = row_d2(m, lane);
        li[y * 64 + lane] = row_d2(~m, lane);
    }
    __syncthreads();

    float ao[8], ai[8];
    #pragma unroll
    for (int k = 0; k < 8; ++k) { ao[k] = 3.0e38f; ai[k] = 3.0e38f; }
    MINPLUS_BODY(lo, li, ao, ai, lane, w)

    size_t vol = (size_t)v * SPATIAL;
    #pragma unroll
    for (int k = 0; k < 8; ++k) {
        int i = w * 8 + k;
        size_t g = vol + (size_t)z * 4096 + (size_t)i * 64 + lane;
        dtOut[g] = ao[k];
        dtIn[g]  = ai[k];
    }
}

// Windowed z-DT on both fields + sdf + softmax prob + volume reduction.
__global__ __launch_bounds__(512) void dtz_final_kernel(
        const float* __restrict__ dtOut, const float* __restrict__ dtIn,
        const float* __restrict__ preds, float* __restrict__ acc) {
    __shared__ float lo[4096];
    __shared__ float li[4096];
    int blk = blockIdx.x;
    int v = blk >> 6, y = blk & 63;
    int b = v / 3, cls = (v % 3) + 1;
    size_t vol = (size_t)v * SPATIAL;
    int t = threadIdx.x;
    int lane = t & 63, w = t >> 6;   // w in [0,8)

    #pragma unroll
    for (int k = 0; k < 8; ++k) {
        int idx = k * 512 + t;
        int zz = idx >> 6, x = idx & 63;
        size_t g = vol + (size_t)zz * 4096 + (size_t)y * 64 + x;
        lo[idx] = dtOut[g];
        li[idx] = dtIn[g];
    }
    __syncthreads();

    float ao[8], ai[8];
    #pragma unroll
    for (int k = 0; k < 8; ++k) { ao[k] = 3.0e38f; ai[k] = 3.0e38f; }
    MINPLUS_BODY(lo, li, ao, ai, lane, w)

    float partial = 0.0f;
    const float* pbase = preds + (size_t)b * 4 * SPATIAL;
    #pragma unroll
    for (int k = 0; k < 8; ++k) {
        int i = w * 8 + k;  // z coordinate
        size_t sp = (size_t)i * 4096 + (size_t)y * 64 + lane;
        float sv = sqrtf(ao[k]) - sqrtf(ai[k]);
        float p0 = pbase[sp], p1 = pbase[SPATIAL + sp];
        float p2 = pbase[2 * SPATIAL + sp], p3 = pbase[3 * SPATIAL + sp];
        float m = fmaxf(fmaxf(p0, p1), fmaxf(p2, p3));
        float e0 = __expf(p0 - m), e1 = __expf(p1 - m);
        float e2 = __expf(p2 - m), e3 = __expf(p3 - m);
        float s = e0 + e1 + e2 + e3;
        float ec = (cls == 1) ? e1 : (cls == 2) ? e2 : e3;
        partial += sv * (ec * __builtin_amdgcn_rcpf(s));
    }
    #pragma unroll
    for (int off = 32; off > 0; off >>= 1)
        partial += __shfl_down(partial, off, 64);
    __shared__ float ws8[8];
    if (lane == 0) ws8[w] = partial;
    __syncthreads();
    if (t == 0) {
        float tot = 0.0f;
        #pragma unroll
        for (int i = 0; i < 8; ++i) tot += ws8[i];
        atomicAdd(&acc[ACC_BOUND + v], tot);
    }
}

__global__ void finalize_kernel(const float* __restrict__ acc, float* __restrict__ out) {
    if (threadIdx.x != 0 || blockIdx.x != 0) return;
    float tsum = 0.0f;
    for (int i = 0; i < 16; ++i) {
        float TP = acc[ACC_TP + i];
        float S  = acc[ACC_SUMP + i];
        float CN = acc[ACC_CNT + i];
        float FP = S - TP;
        float FN = CN - TP;
        tsum += (TP + 1e-5f) / (TP + 0.3f * FP + 0.7f * FN + 1e-5f);
    }
    float l_dice = 1.0f - tsum / 16.0f;
    float l_main = (acc[ACC_FOCAL] + acc[ACC_FOCAL + 1] +
                    acc[ACC_FOCAL + 2] + acc[ACC_FOCAL + 3]) / (float)NVOX;
    float bsum = 0.0f;
    for (int v = 0; v < NVOL; ++v) {
        int b = v / 3, c = (v % 3) + 1;
        float CN = acc[ACC_CNT + b * 4 + c];
        float contrib;
        if (CN <= 0.0f) contrib = 0.0f;
        else if (CN >= (float)SPATIAL) contrib = -acc[ACC_SUMP + b * 4 + c] / (float)SPATIAL;
        else contrib = acc[ACC_BOUND + v] / (float)SPATIAL;
        bsum += contrib;
    }
    float l_bound = bsum / (12.0f + 1e-8f);
    out[0] = l_dice + l_main + 0.01f * l_bound;
}

extern "C" void kernel_launch(void* const* d_in, const int* in_sizes, int n_in,
                              void* d_out, int out_size, void* d_ws, size_t ws_size,
                              hipStream_t stream) {
    const float* preds = (const float*)d_in[0];
    const int* targets = (const int*)d_in[1];
    float* out = (float*)d_out;
    float* ws = (float*)d_ws;
    float* acc = ws;                                   // 64 floats
    float* partials = ws + ACC_N;                      // 4*13*256 floats
    float* dtOut = partials + 4 * NPART * RCHUNK;      // NVOL*SPATIAL
    float* dtIn = dtOut + (size_t)NVOL * SPATIAL;      // NVOL*SPATIAL

    hipLaunchKernelGGL(zero_acc_kernel, dim3(1), dim3(64), 0, stream, acc);
    hipLaunchKernelGGL(reduce_kernel, dim3(4 * RCHUNK), dim3(256), 0, stream,
                       preds, targets, partials);
    hipLaunchKernelGGL(stage2_kernel, dim3(4 * NPART), dim3(256), 0, stream, partials, acc);
    hipLaunchKernelGGL(dtxy_kernel, dim3(NVOL * 64), dim3(512), 0, stream,
                       targets, dtOut, dtIn);
    hipLaunchKernelGGL(dtz_final_kernel, dim3(NVOL * 64), dim3(512), 0, stream,
                       dtOut, dtIn, preds, acc);
    hipLaunchKernelGGL(finalize_kernel, dim3(1), dim3(64), 0, stream, acc, out);
}

// Round 4
// 110.728 us; speedup vs baseline: 2.9389x; 1.0056x over previous
//
#include <hip/hip_runtime.h>
#include <math.h>

#define SPATIAL 262144   // 64^3
#define NVOX    1048576  // 4 * 64^3
#define NVOL    12       // 4 batches * 3 foreground classes
#define FAR_D2  50000    // sentinel: > max genuine d^2 (11907), no u16 overflow
#define NPART   13       // per-block partial values in reduce
#define RCHUNK  256      // reduce chunks per batch

typedef unsigned short u16x2 __attribute__((ext_vector_type(2)));
union pku { unsigned int u; u16x2 v; };

__device__ __forceinline__ unsigned int pk_min(unsigned int a, unsigned int b) {
    pku x, y; x.u = a; y.u = b;
    x.v = __builtin_elementwise_min(x.v, y.v);
    return x.u;
}
__device__ __forceinline__ unsigned int pk_max(unsigned int a, unsigned int b) {
    pku x, y; x.u = a; y.u = b;
    x.v = __builtin_elementwise_max(x.v, y.v);
    return x.u;
}

// ---------------- Tversky/Focal reduction ----------------

__device__ __forceinline__ void voxel_accum(float p0, float p1, float p2, float p3,
                                            int t, float* loc) {
    float m = fmaxf(fmaxf(p0, p1), fmaxf(p2, p3));
    float e0 = __expf(p0 - m), e1 = __expf(p1 - m);
    float e2 = __expf(p2 - m), e3 = __expf(p3 - m);
    float s = e0 + e1 + e2 + e3;
    float inv = __builtin_amdgcn_rcpf(s);
    float q0 = e0 * inv, q1 = e1 * inv, q2 = e2 * inv, q3 = e3 * inv;
    float pl = (t == 0) ? p0 : (t == 1) ? p1 : (t == 2) ? p2 : p3;
    float ce = __logf(s) + (m - pl);           // lse - pl
    float qt = (t == 0) ? q0 : (t == 1) ? q1 : (t == 2) ? q2 : q3;  // = exp(-ce)
    float om = 1.0f - qt;
    loc[0] += q0; loc[1] += q1; loc[2] += q2; loc[3] += q3;
    if (t == 0)      { loc[4] += q0; loc[8]  += 1.f; }
    else if (t == 1) { loc[5] += q1; loc[9]  += 1.f; }
    else if (t == 2) { loc[6] += q2; loc[10] += 1.f; }
    else             { loc[7] += q3; loc[11] += 1.f; }
    loc[12] += om * om * ce;
}

// 1024 blocks; block bb: batch b = bb>>8, chunk = bb&255 (1024 voxels).
__global__ __launch_bounds__(256) void reduce_kernel(
        const float* __restrict__ preds, const int* __restrict__ targets,
        float* __restrict__ partials) {
    int bb = blockIdx.x;
    int b = bb >> 8, chunk = bb & 255;
    int tid = threadIdx.x;
    const float* pb = preds + (size_t)b * 4 * SPATIAL;
    const int* tb = targets + b * SPATIAL;
    float loc[NPART];
    #pragma unroll
    for (int k = 0; k < NPART; ++k) loc[k] = 0.0f;

    int sp = chunk * 1024 + tid * 4;
    float4 P0 = *(const float4*)(pb + 0 * SPATIAL + sp);
    float4 P1 = *(const float4*)(pb + 1 * SPATIAL + sp);
    float4 P2 = *(const float4*)(pb + 2 * SPATIAL + sp);
    float4 P3 = *(const float4*)(pb + 3 * SPATIAL + sp);
    int4   T  = *(const int4*)(tb + sp);
    voxel_accum(P0.x, P1.x, P2.x, P3.x, T.x, loc);
    voxel_accum(P0.y, P1.y, P2.y, P3.y, T.y, loc);
    voxel_accum(P0.z, P1.z, P2.z, P3.z, T.z, loc);
    voxel_accum(P0.w, P1.w, P2.w, P3.w, T.w, loc);

    int lane = tid & 63, w = tid >> 6;
    #pragma unroll
    for (int k = 0; k < NPART; ++k) {
        float v = loc[k];
        #pragma unroll
        for (int off = 32; off > 0; off >>= 1)
            v += __shfl_down(v, off, 64);
        loc[k] = v;
    }
    __shared__ float sred[NPART][4];
    if (lane == 0) {
        #pragma unroll
        for (int k = 0; k < NPART; ++k) sred[k][w] = loc[k];
    }
    __syncthreads();
    if (tid < NPART) {
        float tot = sred[tid][0] + sred[tid][1] + sred[tid][2] + sred[tid][3];
        partials[(b * NPART + tid) * RCHUNK + chunk] = tot;
    }
}

// ---------------- DT (packed u16 pair: lo=out-field, hi=in-field) ----------------

// squared distance (int) from lane i to nearest set bit in 64-bit row mask.
__device__ __forceinline__ int row_d2i(unsigned long long m, int i) {
    if (m == 0ull) return FAR_D2;
    unsigned long long right = m >> i;
    unsigned long long left  = m << (63 - i);
    int dr = right ? __builtin_ctzll(right) : 1000;
    int dl = left  ? __builtin_clzll(left)  : 1000;
    int d = (dr < dl) ? dr : dl;
    return d * d;
}

// Windowed exact packed min-plus; wave W owns i in [8W, 8W+8), lane = column.
// Skipped j satisfy d^2 >= all accumulators (both halves) -> exact.
#define MINPLUS_PK(LA, ACC, LANE, W)                                            \
    {                                                                           \
        const int base = (W) * 8;                                               \
        _Pragma("unroll")                                                       \
        for (int jj = 0; jj < 8; ++jj) {                                        \
            unsigned int wv = LA[(base + jj) * 64 + (LANE)];                    \
            _Pragma("unroll")                                                   \
            for (int k = 0; k < 8; ++k) {                                       \
                int d = k - jj;                                                 \
                unsigned int dd = (unsigned int)(d * d);                        \
                ACC[k] = pk_min(ACC[k], wv + (dd | (dd << 16)));                \
            }                                                                   \
        }                                                                       \
        const int el_max = base, er_max = 56 - base;                            \
        int t = 1;                                                              \
        while (true) {                                                          \
            unsigned int am = 0;                                                \
            _Pragma("unroll")                                                   \
            for (int k = 0; k < 8; ++k) am = pk_max(am, ACC[k]);                \
            _Pragma("unroll")                                                   \
            for (int off = 32; off > 0; off >>= 1)                              \
                am = pk_max(am, (unsigned int)__shfl_xor((int)am, off, 64));    \
            int amx = (int)(am & 0xFFFFu), amy = (int)(am >> 16);               \
            int mm = (amx > amy) ? amx : amy;                                   \
            int dmax = (int)sqrtf((float)mm) + 1;  /* overshoot-safe bound */   \
            int Tl = (dmax < el_max) ? dmax : el_max;                           \
            int Tr = (dmax < er_max) ? dmax : er_max;                           \
            int T = (Tl > Tr) ? Tl : Tr;                                        \
            if (t > T) break;                                                   \
            int tend = (T < t + 3) ? T : (t + 3);                               \
            for (; t <= tend; ++t) {                                            \
                if (t <= Tl) {                                                  \
                    unsigned int wv = LA[(base - t) * 64 + (LANE)];             \
                    _Pragma("unroll")                                           \
                    for (int k = 0; k < 8; ++k) {                               \
                        int d = t + k;                                          \
                        unsigned int dd = (unsigned int)(d * d);                \
                        ACC[k] = pk_min(ACC[k], wv + (dd | (dd << 16)));        \
                    }                                                           \
                }                                                               \
                if (t <= Tr) {                                                  \
                    unsigned int wv = LA[(base + 7 + t) * 64 + (LANE)];         \
                    _Pragma("unroll")                                           \
                    for (int k = 0; k < 8; ++k) {                               \
                        int d = t + 7 - k;                                      \
                        unsigned int dd = (unsigned int)(d * d);                \
                        ACC[k] = pk_min(ACC[k], wv + (dd | (dd << 16)));        \
                    }                                                           \
                }                                                               \
            }                                                                   \
        }                                                                       \
    }

// Fused x-DT (ballot, both fields packed) + windowed y-DT for one (v,z) slice.
__global__ __launch_bounds__(512) void dtxy_kernel(
        const int* __restrict__ targets, unsigned int* __restrict__ dtp) {
    __shared__ unsigned int la[4096];
    int blk = blockIdx.x;
    int v = blk >> 6, z = blk & 63;
    int b = v / 3, cls = (v % 3) + 1;
    const int* tp = targets + b * SPATIAL + z * 4096;
    int t = threadIdx.x, lane = t & 63, w = t >> 6;   // w in [0,8)

    #pragma unroll
    for (int k = 0; k < 8; ++k) {
        int y = w * 8 + k;
        int tv = tp[y * 64 + lane];
        unsigned long long m = __ballot(tv == cls);
        int do2 = row_d2i(m, lane);
        int di2 = row_d2i(~m, lane);
        la[y * 64 + lane] = (unsigned int)do2 | ((unsigned int)di2 << 16);
    }
    __syncthreads();

    unsigned int acc[8];
    #pragma unroll
    for (int k = 0; k < 8; ++k) acc[k] = 0xFFFFFFFFu;
    MINPLUS_PK(la, acc, lane, w)

    size_t vol = (size_t)v * SPATIAL;
    #pragma unroll
    for (int k = 0; k < 8; ++k) {
        int i = w * 8 + k;
        dtp[vol + (size_t)z * 4096 + (size_t)i * 64 + lane] = acc[k];
    }
}

// Windowed z-DT (packed) + sdf + softmax prob + per-block partial (no atomics).
__global__ __launch_bounds__(512) void dtz_final_kernel(
        const unsigned int* __restrict__ dtp, const float* __restrict__ preds,
        float* __restrict__ bound) {
    __shared__ unsigned int la[4096];
    int blk = blockIdx.x;
    int v = blk >> 6, y = blk & 63;
    int b = v / 3, cls = (v % 3) + 1;
    size_t vol = (size_t)v * SPATIAL;
    int t = threadIdx.x, lane = t & 63, w = t >> 6;   // w in [0,8)

    #pragma unroll
    for (int k = 0; k < 8; ++k) {
        int idx = k * 512 + t;
        int zz = idx >> 6, x = idx & 63;
        la[idx] = dtp[vol + (size_t)zz * 4096 + (size_t)y * 64 + x];
    }
    __syncthreads();

    unsigned int acc[8];
    #pragma unroll
    for (int k = 0; k < 8; ++k) acc[k] = 0xFFFFFFFFu;
    MINPLUS_PK(la, acc, lane, w)

    float partial = 0.0f;
    const float* pbase = preds + (size_t)b * 4 * SPATIAL;
    #pragma unroll
    for (int k = 0; k < 8; ++k) {
        int i = w * 8 + k;  // z coordinate
        size_t sp = (size_t)i * 4096 + (size_t)y * 64 + lane;
        float dout = (float)(acc[k] & 0xFFFFu);
        float din  = (float)(acc[k] >> 16);
        float sv = sqrtf(dout) - sqrtf(din);
        float p0 = pbase[sp], p1 = pbase[SPATIAL + sp];
        float p2 = pbase[2 * SPATIAL + sp], p3 = pbase[3 * SPATIAL + sp];
        float m = fmaxf(fmaxf(p0, p1), fmaxf(p2, p3));
        float e0 = __expf(p0 - m), e1 = __expf(p1 - m);
        float e2 = __expf(p2 - m), e3 = __expf(p3 - m);
        float s = e0 + e1 + e2 + e3;
        float ec = (cls == 1) ? e1 : (cls == 2) ? e2 : e3;
        partial += sv * (ec * __builtin_amdgcn_rcpf(s));
    }
    #pragma unroll
    for (int off = 32; off > 0; off >>= 1)
        partial += __shfl_down(partial, off, 64);
    __shared__ float ws8[8];
    if (lane == 0) ws8[w] = partial;
    __syncthreads();
    if (t == 0) {
        float tot = 0.0f;
        #pragma unroll
        for (int i = 0; i < 8; ++i) tot += ws8[i];
        bound[blk] = tot;   // blk = v*64 + y
    }
}

// Single block: reduce 52x256 partials + 12x64 bound partials, emit loss.
__global__ __launch_bounds__(256) void final_kernel(
        const float* __restrict__ partials, const float* __restrict__ bound,
        float* __restrict__ out) {
    __shared__ float rowsum[52];
    __shared__ float bsum[12];
    int tid = threadIdx.x, lane = tid & 63, w = tid >> 6;

    for (int r = w; r < 52; r += 4) {
        const float* p = partials + r * RCHUNK;
        float v = p[lane] + p[64 + lane] + p[128 + lane] + p[192 + lane];
        #pragma unroll
        for (int off = 32; off > 0; off >>= 1)
            v += __shfl_down(v, off, 64);
        if (lane == 0) rowsum[r] = v;
    }
    for (int r = w; r < 12; r += 4) {
        float v = bound[r * 64 + lane];
        #pragma unroll
        for (int off = 32; off > 0; off >>= 1)
            v += __shfl_down(v, off, 64);
        if (lane == 0) bsum[r] = v;
    }
    __syncthreads();
    if (tid != 0) return;

    float tsum = 0.0f;
    for (int b = 0; b < 4; ++b)
        for (int c = 0; c < 4; ++c) {
            float S  = rowsum[b * NPART + c];
            float TP = rowsum[b * NPART + 4 + c];
            float CN = rowsum[b * NPART + 8 + c];
            float FP = S - TP;
            float FN = CN - TP;
            tsum += (TP + 1e-5f) / (TP + 0.3f * FP + 0.7f * FN + 1e-5f);
        }
    float l_dice = 1.0f - tsum / 16.0f;
    float l_main = (rowsum[12] + rowsum[NPART + 12] +
                    rowsum[2 * NPART + 12] + rowsum[3 * NPART + 12]) / (float)NVOX;
    float bs = 0.0f;
    for (int v = 0; v < NVOL; ++v) {
        int b = v / 3, c = (v % 3) + 1;
        float CN = rowsum[b * NPART + 8 + c];
        float contrib;
        if (CN <= 0.0f) contrib = 0.0f;
        else if (CN >= (float)SPATIAL) contrib = -rowsum[b * NPART + c] / (float)SPATIAL;
        else contrib = bsum[v] / (float)SPATIAL;
        bs += contrib;
    }
    float l_bound = bs / (12.0f + 1e-8f);
    out[0] = l_dice + l_main + 0.01f * l_bound;
}

extern "C" void kernel_launch(void* const* d_in, const int* in_sizes, int n_in,
                              void* d_out, int out_size, void* d_ws, size_t ws_size,
                              hipStream_t stream) {
    const float* preds = (const float*)d_in[0];
    const int* targets = (const int*)d_in[1];
    float* out = (float*)d_out;
    float* ws = (float*)d_ws;
    float* partials = ws;                                   // 4*13*256 floats
    float* bound = ws + 4 * NPART * RCHUNK;                 // 768 floats
    unsigned int* dtp = (unsigned int*)(ws + 4 * NPART * RCHUNK + NVOL * 64); // 12 MB

    hipLaunchKernelGGL(reduce_kernel, dim3(4 * RCHUNK), dim3(256), 0, stream,
                       preds, targets, partials);
    hipLaunchKernelGGL(dtxy_kernel, dim3(NVOL * 64), dim3(512), 0, stream,
                       targets, dtp);
    hipLaunchKernelGGL(dtz_final_kernel, dim3(NVOL * 64), dim3(512), 0, stream,
                       dtp, preds, bound);
    hipLaunchKernelGGL(final_kernel, dim3(1), dim3(256), 0, stream,
                       partials, bound, out);
}

// Round 5
// 104.017 us; speedup vs baseline: 3.1285x; 1.0645x over previous
//
#include <hip/hip_runtime.h>
#include <math.h>

#define SPATIAL 262144   // 64^3
#define NVOX    1048576  // 4 * 64^3
#define NVOL    12       // 4 batches * 3 foreground classes
#define FAR_D2  50000    // sentinel: > max genuine d^2 (11907), no u16 overflow
#define NPART   13       // Tversky/focal partial values per batch

typedef unsigned short u16x2 __attribute__((ext_vector_type(2)));
union pku { unsigned int u; u16x2 v; };

__device__ __forceinline__ unsigned int pk_min(unsigned int a, unsigned int b) {
    pku x, y; x.u = a; y.u = b;
    x.v = __builtin_elementwise_min(x.v, y.v);
    return x.u;
}
__device__ __forceinline__ unsigned int pk_max(unsigned int a, unsigned int b) {
    pku x, y; x.u = a; y.u = b;
    x.v = __builtin_elementwise_max(x.v, y.v);
    return x.u;
}

// squared distance (int) from lane i to nearest set bit in 64-bit row mask.
__device__ __forceinline__ int row_d2i(unsigned long long m, int i) {
    if (m == 0ull) return FAR_D2;
    unsigned long long right = m >> i;
    unsigned long long left  = m << (63 - i);
    int dr = right ? __builtin_ctzll(right) : 1000;
    int dl = left  ? __builtin_clzll(left)  : 1000;
    int d = (dr < dl) ? dr : dl;
    return d * d;
}

// Windowed exact packed min-plus; wave W owns i in [8W, 8W+8), lane = column.
// Skipped j satisfy d^2 >= all accumulators (both halves) -> exact.
// Bound refreshed every 8 expansion steps (stale bound only over-scans).
#define MINPLUS_PK(LA, ACC, LANE, W)                                            \
    {                                                                           \
        const int base = (W) * 8;                                               \
        _Pragma("unroll")                                                       \
        for (int jj = 0; jj < 8; ++jj) {                                        \
            unsigned int wv = LA[(base + jj) * 64 + (LANE)];                    \
            _Pragma("unroll")                                                   \
            for (int k = 0; k < 8; ++k) {                                       \
                int d = k - jj;                                                 \
                unsigned int dd = (unsigned int)(d * d);                        \
                ACC[k] = pk_min(ACC[k], wv + (dd | (dd << 16)));                \
            }                                                                   \
        }                                                                       \
        const int el_max = base, er_max = 56 - base;                            \
        int t = 1;                                                              \
        while (true) {                                                          \
            unsigned int am = 0;                                                \
            _Pragma("unroll")                                                   \
            for (int k = 0; k < 8; ++k) am = pk_max(am, ACC[k]);                \
            _Pragma("unroll")                                                   \
            for (int off = 32; off > 0; off >>= 1)                              \
                am = pk_max(am, (unsigned int)__shfl_xor((int)am, off, 64));    \
            int amx = (int)(am & 0xFFFFu), amy = (int)(am >> 16);               \
            int mm = (amx > amy) ? amx : amy;                                   \
            int dmax = (int)sqrtf((float)mm) + 1;  /* overshoot-safe bound */   \
            int Tl = (dmax < el_max) ? dmax : el_max;                           \
            int Tr = (dmax < er_max) ? dmax : er_max;                           \
            int T = (Tl > Tr) ? Tl : Tr;                                        \
            if (t > T) break;                                                   \
            int tend = (T < t + 7) ? T : (t + 7);                               \
            for (; t <= tend; ++t) {                                            \
                if (t <= Tl) {                                                  \
                    unsigned int wv = LA[(base - t) * 64 + (LANE)];             \
                    _Pragma("unroll")                                           \
                    for (int k = 0; k < 8; ++k) {                               \
                        int d = t + k;                                          \
                        unsigned int dd = (unsigned int)(d * d);                \
                        ACC[k] = pk_min(ACC[k], wv + (dd | (dd << 16)));        \
                    }                                                           \
                }                                                               \
                if (t <= Tr) {                                                  \
                    unsigned int wv = LA[(base + 7 + t) * 64 + (LANE)];         \
                    _Pragma("unroll")                                           \
                    for (int k = 0; k < 8; ++k) {                               \
                        int d = t + 7 - k;                                      \
                        unsigned int dd = (unsigned int)(d * d);                \
                        ACC[k] = pk_min(ACC[k], wv + (dd | (dd << 16)));        \
                    }                                                           \
                }                                                               \
            }                                                                   \
        }                                                                       \
    }

// Fused x-DT (ballot, both fields packed) + windowed y-DT for one (v,z) slice.
__global__ __launch_bounds__(512) void dtxy_kernel(
        const int* __restrict__ targets, unsigned int* __restrict__ dtp) {
    __shared__ unsigned int la[4096];
    int blk = blockIdx.x;
    int v = blk >> 6, z = blk & 63;
    int b = v / 3, cls = (v % 3) + 1;
    const int* tp = targets + b * SPATIAL + z * 4096;
    int t = threadIdx.x, lane = t & 63, w = t >> 6;   // w in [0,8)

    #pragma unroll
    for (int k = 0; k < 8; ++k) {
        int y = w * 8 + k;
        int tv = tp[y * 64 + lane];
        unsigned long long m = __ballot(tv == cls);
        int do2 = row_d2i(m, lane);
        int di2 = row_d2i(~m, lane);
        la[y * 64 + lane] = (unsigned int)do2 | ((unsigned int)di2 << 16);
    }
    __syncthreads();

    unsigned int acc[8];
    #pragma unroll
    for (int k = 0; k < 8; ++k) acc[k] = 0xFFFFFFFFu;
    MINPLUS_PK(la, acc, lane, w)

    size_t vol = (size_t)v * SPATIAL;
    #pragma unroll
    for (int k = 0; k < 8; ++k) {
        int i = w * 8 + k;
        dtp[vol + (size_t)z * 4096 + (size_t)i * 64 + lane] = acc[k];
    }
}

// Windowed z-DT (packed) + sdf + softmax + boundary partial; cls==1 blocks
// additionally accumulate the 13 Tversky/focal quantities for their batch
// (each batch's 64 cls-1 blocks tile the volume exactly once).
__global__ __launch_bounds__(512) void dtz_fused_kernel(
        const unsigned int* __restrict__ dtp, const float* __restrict__ preds,
        const int* __restrict__ targets,
        float* __restrict__ bound, float* __restrict__ rpart) {
    __shared__ unsigned int la[4096];
    int blk = blockIdx.x;
    int v = blk >> 6, y = blk & 63;
    int b = v / 3, cls = (v % 3) + 1;
    size_t vol = (size_t)v * SPATIAL;
    int t = threadIdx.x, lane = t & 63, w = t >> 6;   // w in [0,8)

    #pragma unroll
    for (int k = 0; k < 8; ++k) {
        int idx = k * 512 + t;
        int zz = idx >> 6, x = idx & 63;
        la[idx] = dtp[vol + (size_t)zz * 4096 + (size_t)y * 64 + x];
    }
    __syncthreads();

    unsigned int acc[8];
    #pragma unroll
    for (int k = 0; k < 8; ++k) acc[k] = 0xFFFFFFFFu;
    MINPLUS_PK(la, acc, lane, w)

    const bool doRed = (cls == 1);   // wave-uniform per block
    float loc[NPART];
    #pragma unroll
    for (int k = 0; k < NPART; ++k) loc[k] = 0.0f;

    float partial = 0.0f;
    const float* pbase = preds + (size_t)b * 4 * SPATIAL;
    const int* tbase = targets + b * SPATIAL;
    #pragma unroll
    for (int k = 0; k < 8; ++k) {
        int i = w * 8 + k;  // z coordinate
        size_t sp = (size_t)i * 4096 + (size_t)y * 64 + lane;
        float dout = (float)(acc[k] & 0xFFFFu);
        float din  = (float)(acc[k] >> 16);
        float sv = sqrtf(dout) - sqrtf(din);
        float p0 = pbase[sp], p1 = pbase[SPATIAL + sp];
        float p2 = pbase[2 * SPATIAL + sp], p3 = pbase[3 * SPATIAL + sp];
        float m = fmaxf(fmaxf(p0, p1), fmaxf(p2, p3));
        float e0 = __expf(p0 - m), e1 = __expf(p1 - m);
        float e2 = __expf(p2 - m), e3 = __expf(p3 - m);
        float s = e0 + e1 + e2 + e3;
        float inv = __builtin_amdgcn_rcpf(s);
        float ec = (cls == 1) ? e1 : (cls == 2) ? e2 : e3;
        partial += sv * (ec * inv);
        if (doRed) {
            int tv = tbase[sp];
            float q0 = e0 * inv, q1 = e1 * inv, q2 = e2 * inv, q3 = e3 * inv;
            float pl = (tv == 0) ? p0 : (tv == 1) ? p1 : (tv == 2) ? p2 : p3;
            float ce = __logf(s) + (m - pl);           // lse - pl
            float qt = (tv == 0) ? q0 : (tv == 1) ? q1 : (tv == 2) ? q2 : q3;
            float om = 1.0f - qt;
            loc[0] += q0; loc[1] += q1; loc[2] += q2; loc[3] += q3;
            if (tv == 0)      { loc[4] += q0; loc[8]  += 1.f; }
            else if (tv == 1) { loc[5] += q1; loc[9]  += 1.f; }
            else if (tv == 2) { loc[6] += q2; loc[10] += 1.f; }
            else              { loc[7] += q3; loc[11] += 1.f; }
            loc[12] += om * om * ce;
        }
    }

    #pragma unroll
    for (int off = 32; off > 0; off >>= 1)
        partial += __shfl_down(partial, off, 64);
    __shared__ float ws8[8];
    if (lane == 0) ws8[w] = partial;

    if (doRed) {
        __shared__ float sred[NPART][8];
        #pragma unroll
        for (int k = 0; k < NPART; ++k) {
            float vv = loc[k];
            #pragma unroll
            for (int off = 32; off > 0; off >>= 1)
                vv += __shfl_down(vv, off, 64);
            loc[k] = vv;
        }
        if (lane == 0) {
            #pragma unroll
            for (int k = 0; k < NPART; ++k) sred[k][w] = loc[k];
        }
        __syncthreads();
        if (t < NPART) {
            float tot = 0.0f;
            #pragma unroll
            for (int i = 0; i < 8; ++i) tot += sred[t][i];
            rpart[(b * NPART + t) * 64 + y] = tot;
        }
    } else {
        __syncthreads();
    }
    if (t == 0) {
        float tot = 0.0f;
        #pragma unroll
        for (int i = 0; i < 8; ++i) tot += ws8[i];
        bound[blk] = tot;   // blk = v*64 + y
    }
}

// Single block: reduce 52x64 Tversky/focal partials + 12x64 bound partials.
__global__ __launch_bounds__(256) void final_kernel(
        const float* __restrict__ rpart, const float* __restrict__ bound,
        float* __restrict__ out) {
    __shared__ float rowsum[52];
    __shared__ float bsum[12];
    int tid = threadIdx.x, lane = tid & 63, w = tid >> 6;

    for (int r = w; r < 52; r += 4) {
        float v = rpart[r * 64 + lane];
        #pragma unroll
        for (int off = 32; off > 0; off >>= 1)
            v += __shfl_down(v, off, 64);
        if (lane == 0) rowsum[r] = v;
    }
    for (int r = w; r < 12; r += 4) {
        float v = bound[r * 64 + lane];
        #pragma unroll
        for (int off = 32; off > 0; off >>= 1)
            v += __shfl_down(v, off, 64);
        if (lane == 0) bsum[r] = v;
    }
    __syncthreads();
    if (tid != 0) return;

    float tsum = 0.0f;
    for (int b = 0; b < 4; ++b)
        for (int c = 0; c < 4; ++c) {
            float S  = rowsum[b * NPART + c];
            float TP = rowsum[b * NPART + 4 + c];
            float CN = rowsum[b * NPART + 8 + c];
            float FP = S - TP;
            float FN = CN - TP;
            tsum += (TP + 1e-5f) / (TP + 0.3f * FP + 0.7f * FN + 1e-5f);
        }
    float l_dice = 1.0f - tsum / 16.0f;
    float l_main = (rowsum[12] + rowsum[NPART + 12] +
                    rowsum[2 * NPART + 12] + rowsum[3 * NPART + 12]) / (float)NVOX;
    float bs = 0.0f;
    for (int v = 0; v < NVOL; ++v) {
        int b = v / 3, c = (v % 3) + 1;
        float CN = rowsum[b * NPART + 8 + c];
        float contrib;
        if (CN <= 0.0f) contrib = 0.0f;
        else if (CN >= (float)SPATIAL) contrib = -rowsum[b * NPART + c] / (float)SPATIAL;
        else contrib = bsum[v] / (float)SPATIAL;
        bs += contrib;
    }
    float l_bound = bs / (12.0f + 1e-8f);
    out[0] = l_dice + l_main + 0.01f * l_bound;
}

extern "C" void kernel_launch(void* const* d_in, const int* in_sizes, int n_in,
                              void* d_out, int out_size, void* d_ws, size_t ws_size,
                              hipStream_t stream) {
    const float* preds = (const float*)d_in[0];
    const int* targets = (const int*)d_in[1];
    float* out = (float*)d_out;
    float* ws = (float*)d_ws;
    float* rpart = ws;                                  // 4*13*64 = 3328 floats
    float* bound = ws + 4 * NPART * 64;                 // 768 floats
    unsigned int* dtp = (unsigned int*)(ws + 4 * NPART * 64 + NVOL * 64); // 12 MB

    hipLaunchKernelGGL(dtxy_kernel, dim3(NVOL * 64), dim3(512), 0, stream,
                       targets, dtp);
    hipLaunchKernelGGL(dtz_fused_kernel, dim3(NVOL * 64), dim3(512), 0, stream,
                       dtp, preds, targets, bound, rpart);
    hipLaunchKernelGGL(final_kernel, dim3(1), dim3(256), 0, stream,
                       rpart, bound, out);
}